// Round 20
// baseline (159.274 us; speedup 1.0000x reference)
//
#include <hip/hip_runtime.h>
#include <hip/hip_bf16.h>
#include <stdint.h>

typedef __bf16 bf16;
typedef __bf16 bf16x8 __attribute__((ext_vector_type(8)));
typedef __bf16 bf16x4v __attribute__((ext_vector_type(4)));
typedef float  f32x4  __attribute__((ext_vector_type(4)));
typedef float  f32x16 __attribute__((ext_vector_type(16)));
typedef unsigned int u32x4 __attribute__((ext_vector_type(4)));

#define NB    8
#define SEQ   2048
#define EMB   512
#define NHEAD 8
#define HD    64

static __device__ __forceinline__ f32x4 mfma16(bf16x8 a, bf16x8 b, f32x4 c) {
    return __builtin_amdgcn_mfma_f32_16x16x32_bf16(a, b, c, 0, 0, 0);
}
static __device__ __forceinline__ f32x16 mfma32(bf16x8 a, bf16x8 b, f32x16 c) {
    return __builtin_amdgcn_mfma_f32_32x32x16_bf16(a, b, c, 0, 0, 0);
}
static __device__ __forceinline__ float ex2(float x) {
    float r; asm("v_exp_f32 %0, %1" : "=v"(r) : "v"(x)); return r;
}
static __device__ __forceinline__ unsigned pkbf(float lo, float hi) {
    unsigned d; asm("v_cvt_pk_bf16_f32 %0, %1, %2" : "=v"(d) : "v"(lo), "v"(hi)); return d;
}
static __device__ __forceinline__ void gload_lds16(const void* g, void* l) {
    __builtin_amdgcn_global_load_lds(
        (const __attribute__((address_space(1))) unsigned int*)g,
        (__attribute__((address_space(3))) unsigned int*)l, 16, 0, 0);
}
// inverse of the sigma key->position map (closed form, constant-foldable)
static __device__ __forceinline__ int vposInv(int pos) {
    int p4  = pos >> 4;
    int r   = ((p4 & 1) << 3) | (pos & 7);
    int hi2 = (pos >> 3) & 1;
    return (p4 >> 1) * 32 + ((r & 3) | (hi2 << 2) | ((r >> 2) << 3));
}
#define PRIO1 __builtin_amdgcn_s_setprio(1)
#define PRIO0 __builtin_amdgcn_s_setprio(0)

// ---------------------------------------------------------------------------
// Weights: fp32 [k][n] -> bf16 transposed [n][k], LDS tile-transpose (R14).
// ---------------------------------------------------------------------------
__global__ __launch_bounds__(256) void prep_weights(
    const float* __restrict__ Wv, const float* __restrict__ Wk,
    const float* __restrict__ Wq, const float* __restrict__ Wo,
    bf16* __restrict__ wt)
{
    __shared__ float Ls[64][65];
    const int b    = blockIdx.x;
    const int wsel = b >> 6;
    const int kt   = (b & 63) >> 3;
    const int nt   = b & 7;
    const int t    = threadIdx.x;
    const float* src = (wsel == 0) ? Wv : (wsel == 1) ? Wk : (wsel == 2) ? Wq : Wo;

#pragma unroll
    for (int i = 0; i < 16; ++i) {
        int e = i * 256 + t;
        int k = e >> 6, n = e & 63;
        Ls[k][n] = src[(size_t)(kt * 64 + k) * 512 + nt * 64 + n];
    }
    __syncthreads();
#pragma unroll
    for (int i = 0; i < 16; ++i) {
        int e = i * 256 + t;
        int n = e >> 6, k = e & 63;
        wt[(size_t)wsel * 262144 + (size_t)(nt * 64 + n) * 512 + kt * 64 + k] = (bf16)Ls[k][n];
    }
}

// ---------------------------------------------------------------------------
// R16 fused projection GEMM: 128x128 tiles, 256 thr. z=0 values->VbP (sigma
// image), z=1 keys->Kb, z=2 query->Qb (scaled). (unchanged)
// ---------------------------------------------------------------------------
__global__ __launch_bounds__(256) void proj_fused(
    const float* __restrict__ Av, const float* __restrict__ Ak,
    const float* __restrict__ Aq, const bf16* __restrict__ wt,
    bf16* __restrict__ VbP, bf16* __restrict__ Kb, bf16* __restrict__ Qb,
    float sc)
{
    __shared__ __align__(16) char smem[35328];
    bf16* As = (bf16*)smem;              // stride 72
    char* BsB = smem + 18432;

    const int t    = threadIdx.x;
    const int lane = t & 63;
    const int wave = t >> 6;
    const int wr   = wave >> 1, wc = wave & 1;
    const int l15  = lane & 15, lg = lane >> 4;
    const int z    = blockIdx.z;
    const long row0 = (long)blockIdx.x * 128;
    const int  col0 = blockIdx.y * 128;

    const float* A  = (z == 0) ? Av : (z == 1) ? Ak : Aq;
    const bf16*  Bt = wt + (size_t)z * 262144;
    const float  oscale = (z == 2) ? sc : 1.0f;

    f32x4 acc[4][4];
#pragma unroll
    for (int i = 0; i < 4; i++)
#pragma unroll
        for (int j = 0; j < 4; j++) acc[i][j] = (f32x4){0.f, 0.f, 0.f, 0.f};

    for (int k0 = 0; k0 < 512; k0 += 64) {
        __syncthreads();
#pragma unroll
        for (int i = 0; i < 8; i++) {
            int c  = t + 256 * i;
            int r  = c >> 4;
            int cc = (c & 15) * 4;
            f32x4 v = *(const f32x4*)(A + (row0 + r) * 512 + k0 + cc);
            bf16x4v pk = { (bf16)v[0], (bf16)v[1], (bf16)v[2], (bf16)v[3] };
            *(bf16x4v*)(As + r * 72 + cc) = pk;
        }
#pragma unroll
        for (int i = 0; i < 4; i++) {
            int chunk = i * 4 + wave;
            int c = chunk * 64 + lane;
            int r = c >> 3, u = c & 7;
            gload_lds16(Bt + (size_t)(col0 + r) * 512 + k0 + ((u ^ (r & 7)) << 3),
                        BsB + chunk * 1024);
        }
        __syncthreads();
#pragma unroll
        for (int kc = 0; kc < 64; kc += 32) {
            bf16x8 af[4], bfv[4];
#pragma unroll
            for (int mb = 0; mb < 4; mb++)
                af[mb] = *(bf16x8*)(As + (wr * 64 + mb * 16 + l15) * 72 + kc + lg * 8);
#pragma unroll
            for (int nb = 0; nb < 4; nb++) {
                int row = wc * 64 + nb * 16 + l15;
                bfv[nb] = *(bf16x8*)(BsB + row * 128 + (((lg + (kc >> 3)) ^ (l15 & 7)) << 4));
            }
#pragma unroll
            for (int mb = 0; mb < 4; mb++)
#pragma unroll
                for (int nb = 0; nb < 4; nb++)
                    acc[mb][nb] = mfma16(af[mb], bfv[nb], acc[mb][nb]);
        }
    }

    if (z == 0) {
        __syncthreads();
        bf16* Cs = (bf16*)smem;   // [128][138]
#pragma unroll
        for (int mb = 0; mb < 4; mb++)
#pragma unroll
            for (int nb = 0; nb < 4; nb++)
#pragma unroll
                for (int r = 0; r < 4; r++) {
                    int keyl = wr * 64 + mb * 16 + lg * 4 + r;
                    int dl   = wc * 64 + nb * 16 + l15;
                    Cs[dl * 138 + keyl] = (bf16)acc[mb][nb][r];
                }
        __syncthreads();
        const int n_idx = (int)(row0 >> 11);
        const int key0  = (int)(row0 & 2047);
        const int dl    = t >> 1;
        const int half  = t & 1;
        const int x8    = (dl & 7) << 3;
        bf16* dst = VbP + ((size_t)n_idx * 512 + col0 + dl) * 2048 + key0 + half * 64;
#pragma unroll
        for (int cc = 0; cc < 8; ++cc) {
            bf16x8 v;
#pragma unroll
            for (int j = 0; j < 8; ++j)
                v[j] = Cs[dl * 138 + half * 64 + vposInv((cc * 8 + j) ^ x8)];
            *(bf16x8*)(dst + cc * 8) = v;
        }
    } else {
        bf16* Cp = (z == 1) ? Kb : Qb;
#pragma unroll
        for (int mb = 0; mb < 4; mb++)
#pragma unroll
            for (int nb = 0; nb < 4; nb++)
#pragma unroll
                for (int r = 0; r < 4; r++) {
                    long grow = row0 + wr * 64 + mb * 16 + lg * 4 + r;
                    int  gcol = col0 + wc * 64 + nb * 16 + l15;
                    Cp[grow * 512 + gcol] = (bf16)(acc[mb][nb][r] * oscale);
                }
    }
}

// ---------------------------------------------------------------------------
// R16 FINAL GEMM: Cb(bf16) x Wo + bias -> fp32 out. (unchanged)
// ---------------------------------------------------------------------------
__global__ __launch_bounds__(256) void gemm_final(
    const bf16* __restrict__ Ap, const bf16* __restrict__ Bt,
    float* __restrict__ Cp, const float* __restrict__ bias)
{
    __shared__ __align__(16) char AsM[128 * 128];
    __shared__ __align__(16) bf16 Bs[128][64];

    const int t    = threadIdx.x;
    const int lane = t & 63;
    const int wave = t >> 6;
    const int wr   = wave >> 1, wc = wave & 1;
    const int l15  = lane & 15, lg = lane >> 4;
    const long row0 = (long)blockIdx.x * 128;
    const int  col0 = blockIdx.y * 128;

    f32x4 acc[4][4];
#pragma unroll
    for (int i = 0; i < 4; i++)
#pragma unroll
        for (int j = 0; j < 4; j++) acc[i][j] = (f32x4){0.f, 0.f, 0.f, 0.f};

    for (int k0 = 0; k0 < 512; k0 += 64) {
        __syncthreads();
#pragma unroll
        for (int i = 0; i < 4; i++) {
            int chunk = i * 4 + wave;
            int c = chunk * 64 + lane;
            int r = c >> 3, u = c & 7;
            gload_lds16(Ap + (row0 + r) * 512 + k0 + ((u ^ (r & 7)) << 3),
                        AsM + chunk * 1024);
        }
#pragma unroll
        for (int i = 0; i < 4; i++) {
            int chunk = i * 4 + wave;
            int c = chunk * 64 + lane;
            int r = c >> 3, u = c & 7;
            gload_lds16(Bt + (size_t)(col0 + r) * 512 + k0 + ((u ^ (r & 7)) << 3),
                        (char*)&Bs[0][0] + chunk * 1024);
        }
        __syncthreads();
#pragma unroll
        for (int kc = 0; kc < 64; kc += 32) {
            bf16x8 af[4], bfv[4];
#pragma unroll
            for (int mb = 0; mb < 4; mb++) {
                int row = wr * 64 + mb * 16 + l15;
                af[mb] = *(bf16x8*)(AsM + row * 128 + (((lg + (kc >> 3)) ^ (l15 & 7)) << 4));
            }
#pragma unroll
            for (int nb = 0; nb < 4; nb++) {
                int row = wc * 64 + nb * 16 + l15;
                bfv[nb] = *(bf16x8*)((char*)&Bs[0][0] + row * 128 + (((lg + (kc >> 3)) ^ (l15 & 7)) << 4));
            }
#pragma unroll
            for (int mb = 0; mb < 4; mb++)
#pragma unroll
                for (int nb = 0; nb < 4; nb++)
                    acc[mb][nb] = mfma16(af[mb], bfv[nb], acc[mb][nb]);
        }
    }

#pragma unroll
    for (int mb = 0; mb < 4; mb++)
#pragma unroll
        for (int nb = 0; nb < 4; nb++)
#pragma unroll
            for (int r = 0; r < 4; r++) {
                long grow = row0 + wr * 64 + mb * 16 + lg * 4 + r;
                int  gcol = col0 + wc * 64 + nb * 16 + l15;
                Cp[grow * 512 + gcol] = acc[mb][nb][r] + bias[gcol];
            }
}

// ---------------------------------------------------------------------------
// Flash attention R20: 64q/wave (R16 DS economy) + 64KB-exact LDS (R18) +
// register-free A/B interleave: QK(A),pack(A)->bq, [QK(B),PV(A)] 32-MFMA
// burst, pack(B)->bq, PV(B). bq reused (PV(A) consumes before pack(B)
// rewrites) => VGPR stays at R16's 128. Grid (h,n,qt) 8x8x4, 1 block/CU.
// ---------------------------------------------------------------------------
__global__ __launch_bounds__(512, 2) void attn_kernel(
    const bf16* __restrict__ Qg, const bf16* __restrict__ Kg,
    const bf16* __restrict__ VbP, const int* __restrict__ mask,
    bf16* __restrict__ ctx)
{
    // [0,32768) K bufs 4x8192B; [32768,65536) V bufs 4x8192B. Total 65536.
    __shared__ __align__(16) char smem[65536];

    const int t    = threadIdx.x;
    const int lane = t & 63;
    const int w    = t >> 6;
    const int l31  = lane & 31;
    const int hi   = lane >> 5;
    const int h = blockIdx.x, n = blockIdx.y, qt = blockIdx.z;

    const size_t nbase   = (size_t)n * SEQ;
    const size_t headoff = (size_t)h * 64;
    const int q0 = qt * 512 + w * 64;

    // mask flags (pre-staging, double barrier so staging can't clobber early)
    {
        const int* mp0 = mask + n * SEQ + t * 4;
        int mok = (mp0[0] != 0) & (mp0[1] != 0) & (mp0[2] != 0) & (mp0[3] != 0);
        unsigned long long b = __ballot(mok);
        if (lane == 0) ((int*)smem)[w] = (b == ~0ULL) ? 1 : 0;
    }
    __syncthreads();
    int maskall = 1;
#pragma unroll
    for (int i = 0; i < 8; ++i) maskall &= ((int*)smem)[i];
    __syncthreads();   // all reads done before staging overwrites

    // Q fragments: B-operand, col=q=l31, k-dim d = ds*16 + hi*8 + j
    bf16x8 qf[2][4];
#pragma unroll
    for (int qb = 0; qb < 2; ++qb)
#pragma unroll
        for (int ds = 0; ds < 4; ++ds)
            qf[qb][ds] = *(const bf16x8*)(Qg + (nbase + q0 + qb * 32 + l31) * 512 + headoff + ds * 16 + hi * 8);

    f32x16 o[2][2] = {};
    float l_run[2] = {0.f, 0.f};

    const bf16* kg = Kg + (nbase + w * 8 + (lane >> 3)) * 512 + headoff + (((lane & 7) ^ (lane >> 3)) << 3);
    const bf16* vgP = VbP + ((size_t)n * 512 + h * 64 + w * 8 + (lane >> 3)) * 2048 + ((lane & 7) << 3);
    const int*  mp = mask + n * SEQ;

    // prologue: stage tiles 0,1 (K and V both via gload_lds)
    gload_lds16(kg,                    smem + 0 * 8192 + w * 1024);
    gload_lds16(kg + (size_t)64 * 512, smem + 1 * 8192 + w * 1024);
    gload_lds16(vgP,                   smem + 32768 + 0 * 8192 + w * 1024);
    gload_lds16(vgP + 64,              smem + 32768 + 1 * 8192 + w * 1024);
    __syncthreads();

    f32x16 p[2][2];
    u32x4  bq[2][4];

#define QK_TILE(BUF) do {                                                     \
        const char* kbb = smem + (BUF) * 8192;                                \
        f32x16 zz = {};                                                       \
        p[0][0] = zz; p[0][1] = zz; p[1][0] = zz; p[1][1] = zz;               \
        PRIO1;                                                                \
        _Pragma("unroll")                                                     \
        for (int ds = 0; ds < 4; ++ds) {                                      \
            int sw = (ds * 32 + hi * 16) ^ ((l31 & 7) << 4);                  \
            bf16x8 kf0 = *(const bf16x8*)(kbb + l31 * 128 + sw);              \
            bf16x8 kf1 = *(const bf16x8*)(kbb + (32 + l31) * 128 + sw);       \
            p[0][0] = mfma32(kf0, qf[0][ds], p[0][0]);                        \
            p[1][0] = mfma32(kf0, qf[1][ds], p[1][0]);                        \
            p[0][1] = mfma32(kf1, qf[0][ds], p[0][1]);                        \
            p[1][1] = mfma32(kf1, qf[1][ds], p[1][1]);                        \
        }                                                                     \
        PRIO0;                                                                \
    } while (0)

#define MASK_TILE(T) do {                                                     \
        if (!maskall) {                                                       \
            int mv = mp[(T) * 64 + lane];                                     \
            unsigned long long mb = __ballot(mv != 0);                        \
            if (mb != ~0ULL) {                                                \
                _Pragma("unroll") for (int qb = 0; qb < 2; ++qb)              \
                _Pragma("unroll") for (int kb = 0; kb < 2; ++kb) {            \
                    float* pp = (float*)&p[qb][kb];                           \
                    _Pragma("unroll") for (int r = 0; r < 16; ++r) {          \
                        int kk = kb * 32 + (r & 3) + 8 * (r >> 2) + 4 * hi;   \
                        if (!((mb >> kk) & 1)) pp[r] = -1e30f;                \
                    }                                                         \
                }                                                             \
            }                                                                 \
        }                                                                     \
    } while (0)

// max-free softmax + shuffle-free pack (sigma-permuted V image)
#define SM_PACK do {                                                          \
        _Pragma("unroll")                                                     \
        for (int qb = 0; qb < 2; ++qb) {                                      \
            float* p0 = (float*)&p[qb][0];                                    \
            float* p1 = (float*)&p[qb][1];                                    \
            float sa0 = 0.f, sa1 = 0.f, sa2 = 0.f, sa3 = 0.f;                 \
            _Pragma("unroll") for (int r = 0; r < 16; r += 4) {               \
                float e0 = ex2(p0[r]);   p0[r]   = e0; sa0 += e0;             \
                float e1 = ex2(p0[r+1]); p0[r+1] = e1; sa1 += e1;             \
                float e2 = ex2(p0[r+2]); p0[r+2] = e2; sa2 += e2;             \
                float e3 = ex2(p0[r+3]); p0[r+3] = e3; sa3 += e3;             \
            }                                                                 \
            _Pragma("unroll") for (int r = 0; r < 16; r += 4) {               \
                float e0 = ex2(p1[r]);   p1[r]   = e0; sa0 += e0;             \
                float e1 = ex2(p1[r+1]); p1[r+1] = e1; sa1 += e1;             \
                float e2 = ex2(p1[r+2]); p1[r+2] = e2; sa2 += e2;             \
                float e3 = ex2(p1[r+3]); p1[r+3] = e3; sa3 += e3;             \
            }                                                                 \
            float sl = (sa0 + sa1) + (sa2 + sa3);                             \
            l_run[qb] += sl + __shfl_xor(sl, 32);                             \
            _Pragma("unroll")                                                 \
            for (int ks = 0; ks < 4; ++ks) {                                  \
                float* ps = (ks >> 1) ? p1 : p0;                              \
                int bo = (ks & 1) * 8;                                        \
                bq[qb][ks] = (u32x4){ pkbf(ps[bo + 0], ps[bo + 1]),           \
                                      pkbf(ps[bo + 2], ps[bo + 3]),           \
                                      pkbf(ps[bo + 4], ps[bo + 5]),           \
                                      pkbf(ps[bo + 6], ps[bo + 7]) };         \
            }                                                                 \
        }                                                                     \
    } while (0)

#define PV_TILE(BUF) do {                                                     \
        const char* vbb = smem + 32768 + (BUF) * 8192;                        \
        PRIO1;                                                                \
        _Pragma("unroll")                                                     \
        for (int ks = 0; ks < 4; ++ks) {                                      \
            int sw = (ks * 32 + hi * 16) ^ ((l31 & 7) << 4);                  \
            bf16x8 vf0 = *(const bf16x8*)(vbb + l31 * 128 + sw);              \
            bf16x8 vf1 = *(const bf16x8*)(vbb + (32 + l31) * 128 + sw);       \
            union { u32x4 u; bf16x8 v; } c0, c1;                              \
            c0.u = bq[0][ks]; c1.u = bq[1][ks];                               \
            o[0][0] = mfma32(vf0, c0.v, o[0][0]);                             \
            o[0][1] = mfma32(vf0, c1.v, o[0][1]);                             \
            o[1][0] = mfma32(vf1, c0.v, o[1][0]);                             \
            o[1][1] = mfma32(vf1, c1.v, o[1][1]);                             \
        }                                                                     \
        PRIO0;                                                                \
    } while (0)

    for (int e = 0; e < 16; ++e) {
        const int bA = (e & 1) * 2, bB = bA + 1;
        const int nA = bA ^ 2,      nB = bB ^ 2;
        // T14: issue next-epoch staging early (all async gload_lds)
        if (e < 15) {
            gload_lds16(kg + (size_t)(2 * e + 2) * 64 * 512, smem + nA * 8192 + w * 1024);
            gload_lds16(kg + (size_t)(2 * e + 3) * 64 * 512, smem + nB * 8192 + w * 1024);
            gload_lds16(vgP + (2 * e + 2) * 64, smem + 32768 + nA * 8192 + w * 1024);
            gload_lds16(vgP + (2 * e + 3) * 64, smem + 32768 + nB * 8192 + w * 1024);
        }
        // A: QK + pack -> bq
        QK_TILE(bA);
        MASK_TILE(2 * e);
        SM_PACK;
        // 32-MFMA burst: QK(B) then PV(A) (bq consumed before rewrite)
        QK_TILE(bB);
        PV_TILE(bA);
        // B: pack -> bq, then PV(B)
        MASK_TILE(2 * e + 1);
        SM_PACK;
        PV_TILE(bB);
        __syncthreads();
    }

    // ---- epilogue: O^T -> per-wave LDS transpose -> coalesced bf16 store ----
    // ob aliases smem (dead after final barrier); per-wave chunk, wave-sync.
#pragma unroll
    for (int qb = 0; qb < 2; ++qb) {
        float inv = 1.f / l_run[qb];
        bf16* ob = (bf16*)(smem + w * 4608);   // 32 rows x 72 cols
#pragma unroll
        for (int db = 0; db < 2; ++db) {
            float* oo = (float*)&o[db][qb];
#pragma unroll
            for (int r = 0; r < 16; ++r) {
                int d = db * 32 + (r & 3) + 8 * (r >> 2) + 4 * hi;
                ob[l31 * 72 + d] = (bf16)(oo[r] * inv);
            }
        }
#pragma unroll
        for (int i = 0; i < 2; ++i)
#pragma unroll
            for (int half = 0; half < 2; ++half) {
                int ql = i * 16 + (lane >> 2);
                int d8 = (lane & 3) * 8 + half * 32;
                bf16x8 vv = *(const bf16x8*)(ob + ql * 72 + d8);
                *(bf16x8*)(ctx + (nbase + q0 + qb * 32 + ql) * 512 + headoff + d8) = vv;
            }
    }
#undef QK_TILE
#undef MASK_TILE
#undef SM_PACK
#undef PV_TILE
}

// ---------------------------------------------------------------------------
extern "C" void kernel_launch(void* const* d_in, const int* in_sizes, int n_in,
                              void* d_out, int out_size, void* d_ws, size_t ws_size,
                              hipStream_t stream) {
    (void)in_sizes; (void)n_in; (void)out_size; (void)ws_size;
    const float* values = (const float*)d_in[0];
    const float* keys   = (const float*)d_in[1];
    const float* query  = (const float*)d_in[2];
    const int*   mask   = (const int*)d_in[3];
    const float* Wv = (const float*)d_in[4];
    const float* Wk = (const float*)d_in[5];
    const float* Wq = (const float*)d_in[6];
    const float* Wo = (const float*)d_in[7];
    const float* bo = (const float*)d_in[8];
    float* out = (float*)d_out;

    char* ws = (char*)d_ws;
    bf16* wt  = (bf16*)(ws);                       //  2 MB: 4 x [512][512]
    bf16* Qb  = (bf16*)(ws + ((size_t)2  << 20));  // 16 MB
    bf16* Kb  = (bf16*)(ws + ((size_t)18 << 20));  // 16 MB
    bf16* VbP = (bf16*)(ws + ((size_t)34 << 20));  // 16 MB, sigma image [n][d][key]
    bf16* Cb  = (bf16*)(ws + ((size_t)50 << 20));  // 16 MB

    const float SC = 0.18033688011f;   // 0.125 * log2(e), folded into Q proj

    prep_weights<<<256, 256, 0, stream>>>(Wv, Wk, Wq, Wo, wt);
    proj_fused<<<dim3(128, 4, 3), 256, 0, stream>>>(values, keys, query, wt,
                                                    VbP, Kb, Qb, SC);
    attn_kernel<<<dim3(8, 8, 4), 512, 0, stream>>>(Qb, Kb, VbP, mask, Cb);
    gemm_final<<<dim3(128, 4), 256, 0, stream>>>(Cb, wt + 3 * 262144, out, bo);
}

// Round 21
// 150.653 us; speedup vs baseline: 1.0572x; 1.0572x over previous
//
#include <hip/hip_runtime.h>
#include <hip/hip_bf16.h>
#include <stdint.h>

typedef __bf16 bf16;
typedef __bf16 bf16x8 __attribute__((ext_vector_type(8)));
typedef __bf16 bf16x4v __attribute__((ext_vector_type(4)));
typedef float  f32x4  __attribute__((ext_vector_type(4)));
typedef float  f32x16 __attribute__((ext_vector_type(16)));
typedef unsigned int u32x4 __attribute__((ext_vector_type(4)));

#define NB    8
#define SEQ   2048
#define EMB   512
#define NHEAD 8
#define HD    64

static __device__ __forceinline__ f32x4 mfma16(bf16x8 a, bf16x8 b, f32x4 c) {
    return __builtin_amdgcn_mfma_f32_16x16x32_bf16(a, b, c, 0, 0, 0);
}
static __device__ __forceinline__ f32x16 mfma32(bf16x8 a, bf16x8 b, f32x16 c) {
    return __builtin_amdgcn_mfma_f32_32x32x16_bf16(a, b, c, 0, 0, 0);
}
static __device__ __forceinline__ float ex2(float x) {
    float r; asm("v_exp_f32 %0, %1" : "=v"(r) : "v"(x)); return r;
}
static __device__ __forceinline__ unsigned pkbf(float lo, float hi) {
    unsigned d; asm("v_cvt_pk_bf16_f32 %0, %1, %2" : "=v"(d) : "v"(lo), "v"(hi)); return d;
}
static __device__ __forceinline__ void gload_lds16(const void* g, void* l) {
    __builtin_amdgcn_global_load_lds(
        (const __attribute__((address_space(1))) unsigned int*)g,
        (__attribute__((address_space(3))) unsigned int*)l, 16, 0, 0);
}
// inverse of the sigma key->position map (closed form, constant-foldable)
static __device__ __forceinline__ int vposInv(int pos) {
    int p4  = pos >> 4;
    int r   = ((p4 & 1) << 3) | (pos & 7);
    int hi2 = (pos >> 3) & 1;
    return (p4 >> 1) * 32 + ((r & 3) | (hi2 << 2) | ((r >> 2) << 3));
}
#define PRIO1 __builtin_amdgcn_s_setprio(1)
#define PRIO0 __builtin_amdgcn_s_setprio(0)

// ---------------------------------------------------------------------------
// Weights: fp32 [k][n] -> bf16 transposed [n][k], LDS tile-transpose (R14).
// ---------------------------------------------------------------------------
__global__ __launch_bounds__(256) void prep_weights(
    const float* __restrict__ Wv, const float* __restrict__ Wk,
    const float* __restrict__ Wq, const float* __restrict__ Wo,
    bf16* __restrict__ wt)
{
    __shared__ float Ls[64][65];
    const int b    = blockIdx.x;
    const int wsel = b >> 6;
    const int kt   = (b & 63) >> 3;
    const int nt   = b & 7;
    const int t    = threadIdx.x;
    const float* src = (wsel == 0) ? Wv : (wsel == 1) ? Wk : (wsel == 2) ? Wq : Wo;

#pragma unroll
    for (int i = 0; i < 16; ++i) {
        int e = i * 256 + t;
        int k = e >> 6, n = e & 63;
        Ls[k][n] = src[(size_t)(kt * 64 + k) * 512 + nt * 64 + n];
    }
    __syncthreads();
#pragma unroll
    for (int i = 0; i < 16; ++i) {
        int e = i * 256 + t;
        int n = e >> 6, k = e & 63;
        wt[(size_t)wsel * 262144 + (size_t)(nt * 64 + n) * 512 + kt * 64 + k] = (bf16)Ls[k][n];
    }
}

// ---------------------------------------------------------------------------
// R21 fused projection GEMM: 128x128 tiles, 256 thr, SINGLE-BARRIER pipelined
// K-loop (double-buffered As+Bs; next-step stages issued right after the
// barrier, drained one barrier later with full MFMA cover).
// z=0 values->VbP (sigma image), z=1 keys->Kb, z=2 query->Qb (scaled).
// ---------------------------------------------------------------------------
__global__ __launch_bounds__(256) void proj_fused(
    const float* __restrict__ Av, const float* __restrict__ Ak,
    const float* __restrict__ Aq, const bf16* __restrict__ wt,
    bf16* __restrict__ VbP, bf16* __restrict__ Kb, bf16* __restrict__ Qb,
    float sc)
{
    // As: 2 x [128][72]bf16 = 36864 B at [0,36864); Bs: 2 x 16384 at [36864,69632)
    // z=0 epilogue Cs [128][138] bf16 = 35328 aliases base.
    __shared__ __align__(16) char smem[69632];

    const int t    = threadIdx.x;
    const int lane = t & 63;
    const int wave = t >> 6;
    const int wr   = wave >> 1, wc = wave & 1;
    const int l15  = lane & 15, lg = lane >> 4;
    const int z    = blockIdx.z;
    const long row0 = (long)blockIdx.x * 128;
    const int  col0 = blockIdx.y * 128;

    const float* A  = (z == 0) ? Av : (z == 1) ? Ak : Aq;
    const bf16*  Bt = wt + (size_t)z * 262144;
    const float  oscale = (z == 2) ? sc : 1.0f;

    f32x4 acc[4][4];
#pragma unroll
    for (int i = 0; i < 4; i++)
#pragma unroll
        for (int j = 0; j < 4; j++) acc[i][j] = (f32x4){0.f, 0.f, 0.f, 0.f};

#define STAGE_A(K0, BUF) do {                                                 \
        _Pragma("unroll") for (int i = 0; i < 8; i++) {                       \
            int c  = t + 256 * i;                                             \
            int r  = c >> 4;                                                  \
            int cc = (c & 15) * 4;                                            \
            f32x4 v = *(const f32x4*)(A + (row0 + r) * 512 + (K0) + cc);      \
            bf16x4v pk = { (bf16)v[0], (bf16)v[1], (bf16)v[2], (bf16)v[3] };  \
            *(bf16x4v*)(smem + (BUF) * 18432 + r * 144 + cc * 2) = pk;        \
        }                                                                     \
    } while (0)

#define STAGE_B(K0, BUF) do {                                                 \
        _Pragma("unroll") for (int i = 0; i < 4; i++) {                       \
            int chunk = i * 4 + wave;                                         \
            int c = chunk * 64 + lane;                                        \
            int r = c >> 3, u = c & 7;                                        \
            gload_lds16(Bt + (size_t)(col0 + r) * 512 + (K0) + ((u ^ (r & 7)) << 3), \
                        smem + 36864 + (BUF) * 16384 + chunk * 1024);         \
        }                                                                     \
    } while (0)

    // prologue: stage step 0 into buf 0
    STAGE_B(0, 0);
    STAGE_A(0, 0);

    for (int ks = 0; ks < 8; ++ks) {
        const int cur = ks & 1;
        __syncthreads();   // As(ks) written (lgkm), Bs(ks) arrived (vm)
        if (ks < 7) {
            STAGE_B(64 * (ks + 1), cur ^ 1);   // async, flies across compute
            STAGE_A(64 * (ks + 1), cur ^ 1);
        }
#pragma unroll
        for (int kc = 0; kc < 64; kc += 32) {
            bf16x8 af[4], bfv[4];
#pragma unroll
            for (int mb = 0; mb < 4; mb++)
                af[mb] = *(bf16x8*)(smem + cur * 18432 +
                                    (wr * 64 + mb * 16 + l15) * 144 + (kc + lg * 8) * 2);
#pragma unroll
            for (int nb = 0; nb < 4; nb++) {
                int row = wc * 64 + nb * 16 + l15;
                bfv[nb] = *(bf16x8*)(smem + 36864 + cur * 16384 +
                                     row * 128 + (((lg + (kc >> 3)) ^ (l15 & 7)) << 4));
            }
#pragma unroll
            for (int mb = 0; mb < 4; mb++)
#pragma unroll
                for (int nb = 0; nb < 4; nb++)
                    acc[mb][nb] = mfma16(af[mb], bfv[nb], acc[mb][nb]);
        }
    }
#undef STAGE_A
#undef STAGE_B

    if (z == 0) {
        __syncthreads();
        bf16* Cs = (bf16*)smem;   // [128][138]
#pragma unroll
        for (int mb = 0; mb < 4; mb++)
#pragma unroll
            for (int nb = 0; nb < 4; nb++)
#pragma unroll
                for (int r = 0; r < 4; r++) {
                    int keyl = wr * 64 + mb * 16 + lg * 4 + r;
                    int dl   = wc * 64 + nb * 16 + l15;
                    Cs[dl * 138 + keyl] = (bf16)acc[mb][nb][r];
                }
        __syncthreads();
        const int n_idx = (int)(row0 >> 11);
        const int key0  = (int)(row0 & 2047);
        const int dl    = t >> 1;
        const int half  = t & 1;
        const int x8    = (dl & 7) << 3;
        bf16* dst = VbP + ((size_t)n_idx * 512 + col0 + dl) * 2048 + key0 + half * 64;
#pragma unroll
        for (int cc = 0; cc < 8; ++cc) {
            bf16x8 v;
#pragma unroll
            for (int j = 0; j < 8; ++j)
                v[j] = Cs[dl * 138 + half * 64 + vposInv((cc * 8 + j) ^ x8)];
            *(bf16x8*)(dst + cc * 8) = v;
        }
    } else {
        bf16* Cp = (z == 1) ? Kb : Qb;
#pragma unroll
        for (int mb = 0; mb < 4; mb++)
#pragma unroll
            for (int nb = 0; nb < 4; nb++)
#pragma unroll
                for (int r = 0; r < 4; r++) {
                    long grow = row0 + wr * 64 + mb * 16 + lg * 4 + r;
                    int  gcol = col0 + wc * 64 + nb * 16 + l15;
                    Cp[grow * 512 + gcol] = (bf16)(acc[mb][nb][r] * oscale);
                }
    }
}

// ---------------------------------------------------------------------------
// R21 FINAL GEMM: single-barrier pipelined, A and B both double-buffered
// gload_lds. Cb(bf16) x Wo + bias -> fp32 out.
// ---------------------------------------------------------------------------
__global__ __launch_bounds__(256) void gemm_final(
    const bf16* __restrict__ Ap, const bf16* __restrict__ Bt,
    float* __restrict__ Cp, const float* __restrict__ bias)
{
    // A: 2 x 16384 at [0,32768); B: 2 x 16384 at [32768,65536)
    __shared__ __align__(16) char smem[65536];

    const int t    = threadIdx.x;
    const int lane = t & 63;
    const int wave = t >> 6;
    const int wr   = wave >> 1, wc = wave & 1;
    const int l15  = lane & 15, lg = lane >> 4;
    const long row0 = (long)blockIdx.x * 128;
    const int  col0 = blockIdx.y * 128;

    f32x4 acc[4][4];
#pragma unroll
    for (int i = 0; i < 4; i++)
#pragma unroll
        for (int j = 0; j < 4; j++) acc[i][j] = (f32x4){0.f, 0.f, 0.f, 0.f};

#define STAGE_AB(K0, BUF) do {                                                \
        _Pragma("unroll") for (int i = 0; i < 4; i++) {                       \
            int chunk = i * 4 + wave;                                         \
            int c = chunk * 64 + lane;                                        \
            int r = c >> 3, u = c & 7;                                        \
            gload_lds16(Ap + (row0 + r) * 512 + (K0) + ((u ^ (r & 7)) << 3),  \
                        smem + (BUF) * 16384 + chunk * 1024);                 \
            gload_lds16(Bt + (size_t)(col0 + r) * 512 + (K0) + ((u ^ (r & 7)) << 3), \
                        smem + 32768 + (BUF) * 16384 + chunk * 1024);         \
        }                                                                     \
    } while (0)

    STAGE_AB(0, 0);

    for (int ks = 0; ks < 8; ++ks) {
        const int cur = ks & 1;
        __syncthreads();
        if (ks < 7) STAGE_AB(64 * (ks + 1), cur ^ 1);
#pragma unroll
        for (int kc = 0; kc < 64; kc += 32) {
            bf16x8 af[4], bfv[4];
#pragma unroll
            for (int mb = 0; mb < 4; mb++) {
                int row = wr * 64 + mb * 16 + l15;
                af[mb] = *(bf16x8*)(smem + cur * 16384 +
                                    row * 128 + (((lg + (kc >> 3)) ^ (l15 & 7)) << 4));
            }
#pragma unroll
            for (int nb = 0; nb < 4; nb++) {
                int row = wc * 64 + nb * 16 + l15;
                bfv[nb] = *(bf16x8*)(smem + 32768 + cur * 16384 +
                                     row * 128 + (((lg + (kc >> 3)) ^ (l15 & 7)) << 4));
            }
#pragma unroll
            for (int mb = 0; mb < 4; mb++)
#pragma unroll
                for (int nb = 0; nb < 4; nb++)
                    acc[mb][nb] = mfma16(af[mb], bfv[nb], acc[mb][nb]);
        }
    }
#undef STAGE_AB

#pragma unroll
    for (int mb = 0; mb < 4; mb++)
#pragma unroll
        for (int nb = 0; nb < 4; nb++)
#pragma unroll
            for (int r = 0; r < 4; r++) {
                long grow = row0 + wr * 64 + mb * 16 + lg * 4 + r;
                int  gcol = col0 + wc * 64 + nb * 16 + l15;
                Cp[grow * 512 + gcol] = acc[mb][nb][r] + bias[gcol];
            }
}

// ---------------------------------------------------------------------------
// Flash attention: R18 exact (best measured, 85.0us). 32q/wave, 64KB LDS,
// swapped-QK^T 32x32x16, max-free softmax, sigma V-image via gload_lds.
// ---------------------------------------------------------------------------
__global__ __launch_bounds__(512, 2) void attn_kernel(
    const bf16* __restrict__ Qg, const bf16* __restrict__ Kg,
    const bf16* __restrict__ VbP, const int* __restrict__ mask,
    bf16* __restrict__ ctx)
{
    // [0,32768) K bufs 4x8192B; [32768,65536) V bufs 4x8192B. Total 65536.
    __shared__ __align__(16) char smem[65536];

    const int t    = threadIdx.x;
    const int lane = t & 63;
    const int w    = t >> 6;          // 0..7
    const int l31  = lane & 31;
    const int hi   = lane >> 5;
    const int h = blockIdx.x, n = blockIdx.y, qt = blockIdx.z;

    const size_t nbase   = (size_t)n * SEQ;
    const size_t headoff = (size_t)h * 64;
    const int q0 = qt * 256 + w * 32;

    // mask flags (pre-staging, double barrier so staging can't clobber early)
    {
        const int* mp0 = mask + n * SEQ + t * 4;
        int mok = (mp0[0] != 0) & (mp0[1] != 0) & (mp0[2] != 0) & (mp0[3] != 0);
        unsigned long long b = __ballot(mok);
        if (lane == 0) ((int*)smem)[w] = (b == ~0ULL) ? 1 : 0;
    }
    __syncthreads();
    int maskall = 1;
#pragma unroll
    for (int i = 0; i < 8; ++i) maskall &= ((int*)smem)[i];
    __syncthreads();   // all reads done before staging overwrites

    // Q fragments: B-operand, col=q=l31, k-dim d = ds*16 + hi*8 + j
    bf16x8 qf[4];
#pragma unroll
    for (int ds = 0; ds < 4; ++ds)
        qf[ds] = *(const bf16x8*)(Qg + (nbase + q0 + l31) * 512 + headoff + ds * 16 + hi * 8);

    f32x16 o[2] = {};
    float l_run = 0.f;

    const bf16* kg = Kg + (nbase + w * 8 + (lane >> 3)) * 512 + headoff + (((lane & 7) ^ (lane >> 3)) << 3);
    const bf16* vgP = VbP + ((size_t)n * 512 + h * 64 + w * 8 + (lane >> 3)) * 2048 + ((lane & 7) << 3);
    const int*  mp = mask + n * SEQ;

    // prologue: stage tiles 0,1 (K and V both via gload_lds)
    gload_lds16(kg,                    smem + 0 * 8192 + w * 1024);
    gload_lds16(kg + (size_t)64 * 512, smem + 1 * 8192 + w * 1024);
    gload_lds16(vgP,                   smem + 32768 + 0 * 8192 + w * 1024);
    gload_lds16(vgP + 64,              smem + 32768 + 1 * 8192 + w * 1024);
    __syncthreads();

    f32x16 p[2];
    u32x4  bq[4];

#define QK_TILE(BUF) do {                                                     \
        const char* kbb = smem + (BUF) * 8192;                                \
        f32x16 zz = {};                                                       \
        p[0] = zz; p[1] = zz;                                                 \
        PRIO1;                                                                \
        _Pragma("unroll")                                                     \
        for (int ds = 0; ds < 4; ++ds) {                                      \
            int sw = (ds * 32 + hi * 16) ^ ((l31 & 7) << 4);                  \
            bf16x8 kf0 = *(const bf16x8*)(kbb + l31 * 128 + sw);              \
            bf16x8 kf1 = *(const bf16x8*)(kbb + (32 + l31) * 128 + sw);       \
            p[0] = mfma32(kf0, qf[ds], p[0]);                                 \
            p[1] = mfma32(kf1, qf[ds], p[1]);                                 \
        }                                                                     \
        PRIO0;                                                                \
    } while (0)

#define MASK_TILE(T) do {                                                     \
        if (!maskall) {                                                       \
            int mv = mp[(T) * 64 + lane];                                     \
            unsigned long long mb = __ballot(mv != 0);                        \
            if (mb != ~0ULL) {                                                \
                _Pragma("unroll") for (int kb = 0; kb < 2; ++kb) {            \
                    float* pp = (float*)&p[kb];                               \
                    _Pragma("unroll") for (int r = 0; r < 16; ++r) {          \
                        int kk = kb * 32 + (r & 3) + 8 * (r >> 2) + 4 * hi;   \
                        if (!((mb >> kk) & 1)) pp[r] = -1e30f;                \
                    }                                                         \
                }                                                             \
            }                                                                 \
        }                                                                     \
    } while (0)

// max-free softmax + shuffle-free pack (sigma-permuted V image)
#define SM_PACK do {                                                          \
        float* p0 = (float*)&p[0];                                            \
        float* p1 = (float*)&p[1];                                            \
        float sa0 = 0.f, sa1 = 0.f, sa2 = 0.f, sa3 = 0.f;                     \
        _Pragma("unroll") for (int r = 0; r < 16; r += 4) {                   \
            float e0 = ex2(p0[r]);   p0[r]   = e0; sa0 += e0;                 \
            float e1 = ex2(p0[r+1]); p0[r+1] = e1; sa1 += e1;                 \
            float e2 = ex2(p0[r+2]); p0[r+2] = e2; sa2 += e2;                 \
            float e3 = ex2(p0[r+3]); p0[r+3] = e3; sa3 += e3;                 \
        }                                                                     \
        _Pragma("unroll") for (int r = 0; r < 16; r += 4) {                   \
            float e0 = ex2(p1[r]);   p1[r]   = e0; sa0 += e0;                 \
            float e1 = ex2(p1[r+1]); p1[r+1] = e1; sa1 += e1;                 \
            float e2 = ex2(p1[r+2]); p1[r+2] = e2; sa2 += e2;                 \
            float e3 = ex2(p1[r+3]); p1[r+3] = e3; sa3 += e3;                 \
        }                                                                     \
        float sl = (sa0 + sa1) + (sa2 + sa3);                                 \
        l_run += sl + __shfl_xor(sl, 32);                                     \
        _Pragma("unroll")                                                     \
        for (int ks = 0; ks < 4; ++ks) {                                      \
            float* ps = (ks >> 1) ? p1 : p0;                                  \
            int bo = (ks & 1) * 8;                                            \
            bq[ks] = (u32x4){ pkbf(ps[bo + 0], ps[bo + 1]),                   \
                              pkbf(ps[bo + 2], ps[bo + 3]),                   \
                              pkbf(ps[bo + 4], ps[bo + 5]),                   \
                              pkbf(ps[bo + 6], ps[bo + 7]) };                 \
        }                                                                     \
    } while (0)

#define PV_TILE(BUF) do {                                                     \
        const char* vbb = smem + 32768 + (BUF) * 8192;                        \
        PRIO1;                                                                \
        _Pragma("unroll")                                                     \
        for (int ks = 0; ks < 4; ++ks) {                                      \
            int sw = (ks * 32 + hi * 16) ^ ((l31 & 7) << 4);                  \
            bf16x8 vf0 = *(const bf16x8*)(vbb + l31 * 128 + sw);              \
            bf16x8 vf1 = *(const bf16x8*)(vbb + (32 + l31) * 128 + sw);       \
            union { u32x4 u; bf16x8 v; } c0;                                  \
            c0.u = bq[ks];                                                    \
            o[0] = mfma32(vf0, c0.v, o[0]);                                   \
            o[1] = mfma32(vf1, c0.v, o[1]);                                   \
        }                                                                     \
        PRIO0;                                                                \
    } while (0)

    for (int e = 0; e < 16; ++e) {
        const int bA = (e & 1) * 2, bB = bA + 1;
        const int nA = bA ^ 2,      nB = bB ^ 2;
        // T14: issue next-epoch staging early (all async gload_lds)
        if (e < 15) {
            gload_lds16(kg + (size_t)(2 * e + 2) * 64 * 512, smem + nA * 8192 + w * 1024);
            gload_lds16(kg + (size_t)(2 * e + 3) * 64 * 512, smem + nB * 8192 + w * 1024);
            gload_lds16(vgP + (2 * e + 2) * 64, smem + 32768 + nA * 8192 + w * 1024);
            gload_lds16(vgP + (2 * e + 3) * 64, smem + 32768 + nB * 8192 + w * 1024);
        }
        QK_TILE(bA);
        MASK_TILE(2 * e);
        SM_PACK;
        PV_TILE(bA);
        QK_TILE(bB);
        MASK_TILE(2 * e + 1);
        SM_PACK;
        PV_TILE(bB);
        __syncthreads();
    }

    // ---- epilogue: O^T -> LDS transpose -> coalesced bf16 store ----
    // Ob aliases smem (dead after final barrier).
    {
        float inv = 1.f / l_run;
        bf16* ob = (bf16*)(smem + w * 4608);   // 32 rows x 72 cols
#pragma unroll
        for (int db = 0; db < 2; ++db) {
            float* oo = (float*)&o[db];
#pragma unroll
            for (int r = 0; r < 16; ++r) {
                int d = db * 32 + (r & 3) + 8 * (r >> 2) + 4 * hi;
                ob[l31 * 72 + d] = (bf16)(oo[r] * inv);
            }
        }
        __syncthreads();
#pragma unroll
        for (int i = 0; i < 2; ++i)
#pragma unroll
            for (int half = 0; half < 2; ++half) {
                int ql = i * 16 + (lane >> 2);
                int d8 = (lane & 3) * 8 + half * 32;
                bf16x8 vv = *(const bf16x8*)(ob + ql * 72 + d8);
                *(bf16x8*)(ctx + (nbase + q0 + ql) * 512 + headoff + d8) = vv;
            }
    }
#undef QK_TILE
#undef MASK_TILE
#undef SM_PACK
#undef PV_TILE
}

// ---------------------------------------------------------------------------
extern "C" void kernel_launch(void* const* d_in, const int* in_sizes, int n_in,
                              void* d_out, int out_size, void* d_ws, size_t ws_size,
                              hipStream_t stream) {
    (void)in_sizes; (void)n_in; (void)out_size; (void)ws_size;
    const float* values = (const float*)d_in[0];
    const float* keys   = (const float*)d_in[1];
    const float* query  = (const float*)d_in[2];
    const int*   mask   = (const int*)d_in[3];
    const float* Wv = (const float*)d_in[4];
    const float* Wk = (const float*)d_in[5];
    const float* Wq = (const float*)d_in[6];
    const float* Wo = (const float*)d_in[7];
    const float* bo = (const float*)d_in[8];
    float* out = (float*)d_out;

    char* ws = (char*)d_ws;
    bf16* wt  = (bf16*)(ws);                       //  2 MB: 4 x [512][512]
    bf16* Qb  = (bf16*)(ws + ((size_t)2  << 20));  // 16 MB
    bf16* Kb  = (bf16*)(ws + ((size_t)18 << 20));  // 16 MB
    bf16* VbP = (bf16*)(ws + ((size_t)34 << 20));  // 16 MB, sigma image [n][d][key]
    bf16* Cb  = (bf16*)(ws + ((size_t)50 << 20));  // 16 MB

    const float SC = 0.18033688011f;   // 0.125 * log2(e), folded into Q proj

    prep_weights<<<256, 256, 0, stream>>>(Wv, Wk, Wq, Wo, wt);
    proj_fused<<<dim3(128, 4, 3), 256, 0, stream>>>(values, keys, query, wt,
                                                    VbP, Kb, Qb, SC);
    attn_kernel<<<dim3(8, 8, 8), 512, 0, stream>>>(Qb, Kb, VbP, mask, Cb);
    gemm_final<<<dim3(128, 4), 256, 0, stream>>>(Cb, wt + 3 * 262144, out, bo);
}